// Round 7
// baseline (140.880 us; speedup 1.0000x reference)
//
#include <hip/hip_runtime.h>

// ---------------------------------------------------------------------------
// Causal SDPA, B=8, S=2048, D=64, fp32 in/out.
//   prep_f16: K -> Kh (f16 row-major, PRE-SCALED by log2e/sqrt(D)),
//             V -> Vq (f16 packed [B][S/16][64][16], coalesced PV frags).
//   attn_f16_v5: 32-row q-supertile per 8-wave block; each wave computes TWO
//     16-row q-frags against SHARED K/V/mask registers (halves traffic per
//     output, doubles per-iter MFMA to cover load latency). Operand-swapped
//     S^T = K·Q^T keeps P in registers (no LDS in K-loop); 1-iter-ahead
//     register prefetch; no-max softmax (bounded scores) => plain-sum
//     split-K partials; single LDS block-reduce epilogue.
//     Grid 64x8 = 512 blocks (2/CU), supertile = 63-bx => LPT dispatch.
// Fallback (ws too small): R2-style kernel on fp32 inputs.
// ---------------------------------------------------------------------------

typedef _Float16 f16x8 __attribute__((ext_vector_type(8)));
typedef _Float16 f16x4 __attribute__((ext_vector_type(4)));
typedef float    f32x4 __attribute__((ext_vector_type(4)));

#define MFMA_K32(A, B, C) __builtin_amdgcn_mfma_f32_16x16x32_f16(A, B, C, 0, 0, 0)
#define MFMA_K16(A, B, C) __builtin_amdgcn_mfma_f32_16x16x16f16(A, B, C, 0, 0, 0)

__device__ inline unsigned pack2h(float a, float b) {
    union { _Float16 h[2]; unsigned u; } t;
    t.h[0] = (_Float16)a; t.h[1] = (_Float16)b;
    return t.u;
}

constexpr float CSCALE = 0.18033688011112042f;   // log2(e)/sqrt(64)

// -- prep: Kh = f16(K*CSCALE) [B,S,64]; Vq = f16(V) packed [B,S/16,64,16] ---
__global__ __launch_bounds__(256, 4)
void prep_f16(const float* __restrict__ K, const float* __restrict__ V,
              _Float16* __restrict__ Kh, _Float16* __restrict__ Vq) {
    __shared__ _Float16 sT[64 * 80];          // [d][local_s]
    const int b   = blockIdx.x >> 5;
    const int s0  = (blockIdx.x & 31) * 64;
    const int t   = threadIdx.x;
    const int row = t >> 2;                   // local s 0..63
    const int grp = (t & 3) * 16;             // d group
    const size_t base = ((size_t)b * 2048 + s0 + row) * 64 + grp;
    {   // K: scale + convert, row-major
        union { _Float16 h[16]; f16x8 v[2]; } o;
        const float* p = K + base;
#pragma unroll
        for (int i = 0; i < 16; i += 4) {
            float4 x = *(const float4*)(p + i);
            o.h[i]   = (_Float16)(x.x * CSCALE); o.h[i+1] = (_Float16)(x.y * CSCALE);
            o.h[i+2] = (_Float16)(x.z * CSCALE); o.h[i+3] = (_Float16)(x.w * CSCALE);
        }
        *(f16x8*)(Kh + base) = o.v[0];
        *(f16x8*)(Kh + base + 8) = o.v[1];
    }
    {   // V: convert into LDS transposed sT[d][local_s]
        const float* p = V + base;
#pragma unroll
        for (int i = 0; i < 16; i += 4) {
            float4 x = *(const float4*)(p + i);
            sT[(grp + i    ) * 80 + row] = (_Float16)x.x;
            sT[(grp + i + 1) * 80 + row] = (_Float16)x.y;
            sT[(grp + i + 2) * 80 + row] = (_Float16)x.z;
            sT[(grp + i + 3) * 80 + row] = (_Float16)x.w;
        }
    }
    __syncthreads();
    {   // Vq[b][s>>4][d][s&15]
        const int d = t & 63, g = t >> 6;
        const size_t o = (((size_t)b * 128 + (s0 >> 4) + g) * 64 + d) * 16;
        *(f16x8*)(Vq + o)     = *(const f16x8*)&sT[d * 80 + g * 16];
        *(f16x8*)(Vq + o + 8) = *(const f16x8*)&sT[d * 80 + g * 16 + 8];
    }
}

// -------- v5: 32-row supertile, shared K/V regs, register P ----------------
constexpr int SOSTR = 68;   // padded fp32 row stride for sO (bank spread)

__global__ __launch_bounds__(512, 4)
void attn_f16_v5(const float* __restrict__ Q, const _Float16* __restrict__ Kh,
                 const _Float16* __restrict__ Vq, const int* __restrict__ M,
                 float* __restrict__ O) {
    constexpr int S = 2048, D = 64;

    __shared__ float sO[8][32 * SOSTR];   // 69.6 KB partial O
    __shared__ float sL[8][32];           // partial denominators

    const int tid  = threadIdx.x;
    const int w    = tid >> 6;
    const int lane = tid & 63;
    const int l15  = lane & 15;
    const int quad = lane >> 4;

    const int st    = 63 - (int)blockIdx.x;    // supertile, big first (LPT)
    const int batch = (int)blockIdx.y;
    const int n_kt  = st + 1;                  // 32-key tiles (causal)
    const int qg0   = st * 32;
    const size_t bq = (size_t)batch * S;
    const _Float16* Kb = Kh + bq * D;
    const _Float16* Vb = Vq + bq * D;

    // Q fragments for the two 16-row frags: rows qg0 + f*16 + l15
    f16x8 qf[2][2];
#pragma unroll
    for (int f = 0; f < 2; ++f) {
        const float* qp = Q + (bq + qg0 + f * 16 + l15) * D + quad * 8;
#pragma unroll
        for (int dc = 0; dc < 2; ++dc) {
            float4 x0 = *(const float4*)(qp + dc * 32);
            float4 x1 = *(const float4*)(qp + dc * 32 + 4);
            union { unsigned u[4]; f16x8 v; } t;
            t.u[0] = pack2h(x0.x, x0.y); t.u[1] = pack2h(x0.z, x0.w);
            t.u[2] = pack2h(x1.x, x1.y); t.u[3] = pack2h(x1.z, x1.w);
            qf[f][dc] = t.v;
        }
    }

    f32x4 acc[2][4];
    float lacc[2] = {0.f, 0.f};
#pragma unroll
    for (int f = 0; f < 2; ++f)
#pragma unroll
        for (int c = 0; c < 4; ++c) { acc[f][c][0] = acc[f][c][1] = acc[f][c][2] = acc[f][c][3] = 0.f; }

    // ---- prefetch tile t = w ---------------------------------------------
    f16x8 kn[2][2]; f16x4 vn[2][4]; int4 mn[2];
    if (w < n_kt) {
        const int kb = w * 32;
#pragma unroll
        for (int kg = 0; kg < 2; ++kg)
#pragma unroll
            for (int dc = 0; dc < 2; ++dc)
                kn[kg][dc] = *(const f16x8*)(Kb + (size_t)(kb + kg * 16 + l15) * D + dc * 32 + quad * 8);
#pragma unroll
        for (int kg = 0; kg < 2; ++kg)
#pragma unroll
            for (int c = 0; c < 4; ++c)
                vn[kg][c] = *(const f16x4*)(Vb + ((size_t)((kb >> 4) + kg) * 64 + c * 16 + l15) * 16 + quad * 4);
        mn[0] = *(const int4*)(M + bq + kb + quad * 4);
        mn[1] = *(const int4*)(M + bq + kb + 16 + quad * 4);
    }

    for (int t = w; t < n_kt; t += 8) {
        const int kb = t * 32;
        // rotate prefetched data into current
        f16x8 k00 = kn[0][0], k01 = kn[0][1], k10 = kn[1][0], k11 = kn[1][1];
        f16x4 v00 = vn[0][0], v01 = vn[0][1], v02 = vn[0][2], v03 = vn[0][3];
        f16x4 v10 = vn[1][0], v11 = vn[1][1], v12 = vn[1][2], v13 = vn[1][3];
        union { int a[4]; int4 v; } m0, m1;
        m0.v = mn[0]; m1.v = mn[1];
        // issue next tile's loads
        if (t + 8 < n_kt) {
            const int kb2 = kb + 256;
#pragma unroll
            for (int kg = 0; kg < 2; ++kg)
#pragma unroll
                for (int dc = 0; dc < 2; ++dc)
                    kn[kg][dc] = *(const f16x8*)(Kb + (size_t)(kb2 + kg * 16 + l15) * D + dc * 32 + quad * 8);
#pragma unroll
            for (int kg = 0; kg < 2; ++kg)
#pragma unroll
                for (int c = 0; c < 4; ++c)
                    vn[kg][c] = *(const f16x4*)(Vb + ((size_t)((kb2 >> 4) + kg) * 64 + c * 16 + l15) * 16 + quad * 4);
            mn[0] = *(const int4*)(M + bq + kb2 + quad * 4);
            mn[1] = *(const int4*)(M + bq + kb2 + 16 + quad * 4);
        }

        // ---- both q-frags against shared K/V -----------------------------
#pragma unroll
        for (int f = 0; f < 2; ++f) {
            // S^T = K Q^T : lane holds q = l15 (of frag f), keys = quad*4+r
            f32x4 scT0, scT1;
            {
                f32x4 z; z[0] = z[1] = z[2] = z[3] = 0.f;
                f32x4 y0 = MFMA_K32(k00, qf[f][0], z);
                scT0 = MFMA_K32(k01, qf[f][1], y0);
                f32x4 y1 = MFMA_K32(k10, qf[f][0], z);
                scT1 = MFMA_K32(k11, qf[f][1], y1);
            }
            // masked exp (Kh pre-scaled: exp2 directly)
            const int qrow = qg0 + f * 16 + l15;
            f16x4 pf0, pf1;
            {
                union { _Float16 h[4]; f16x4 v; } pp;
#pragma unroll
                for (int r = 0; r < 4; ++r) {
                    const int key = kb + quad * 4 + r;
                    float e  = __builtin_amdgcn_exp2f(scT0[r]);
                    bool  ok = (key <= qrow) && (m0.a[r] != 0);
                    float pv = ok ? e : 0.f;
                    lacc[f] += pv;
                    pp.h[r] = (_Float16)pv;
                }
                pf0 = pp.v;
#pragma unroll
                for (int r = 0; r < 4; ++r) {
                    const int key = kb + 16 + quad * 4 + r;
                    float e  = __builtin_amdgcn_exp2f(scT1[r]);
                    bool  ok = (key <= qrow) && (m1.a[r] != 0);
                    float pv = ok ? e : 0.f;
                    lacc[f] += pv;
                    pp.h[r] = (_Float16)pv;
                }
                pf1 = pp.v;
            }
            // O += P V
            acc[f][0] = MFMA_K16(pf0, v00, acc[f][0]);
            acc[f][1] = MFMA_K16(pf0, v01, acc[f][1]);
            acc[f][2] = MFMA_K16(pf0, v02, acc[f][2]);
            acc[f][3] = MFMA_K16(pf0, v03, acc[f][3]);
            acc[f][0] = MFMA_K16(pf1, v10, acc[f][0]);
            acc[f][1] = MFMA_K16(pf1, v11, acc[f][1]);
            acc[f][2] = MFMA_K16(pf1, v12, acc[f][2]);
            acc[f][3] = MFMA_K16(pf1, v13, acc[f][3]);
        }
    }

    // denom partials: sum over quads (lanes sharing l15)
#pragma unroll
    for (int f = 0; f < 2; ++f) {
        lacc[f] += __shfl_xor(lacc[f], 16, 64);
        lacc[f] += __shfl_xor(lacc[f], 32, 64);
    }

    // write partials, block-reduce, store
#pragma unroll
    for (int f = 0; f < 2; ++f)
#pragma unroll
        for (int c = 0; c < 4; ++c)
#pragma unroll
            for (int r = 0; r < 4; ++r)
                sO[w][(f * 16 + quad * 4 + r) * SOSTR + c * 16 + l15] = acc[f][c][r];
    if (lane < 16) { sL[w][l15] = lacc[0]; sL[w][16 + l15] = lacc[1]; }
    __syncthreads();
    {
        const int row = tid >> 4;          // 0..31
        const int col = (tid & 15) * 4;    // 0,4,..,60
        float a0 = 0.f, a1 = 0.f, a2 = 0.f, a3 = 0.f, l = 0.f;
#pragma unroll
        for (int w2 = 0; w2 < 8; ++w2) {
            const float* p = &sO[w2][row * SOSTR + col];
            a0 += p[0]; a1 += p[1]; a2 += p[2]; a3 += p[3];
            l  += sL[w2][row];
        }
        const float inv = 1.f / fmaxf(l, 1e-37f);
        float4 o; o.x = a0 * inv; o.y = a1 * inv; o.z = a2 * inv; o.w = a3 * inv;
        *(float4*)(&O[(bq + qg0 + row) * D + col]) = o;
    }
}

// ---------------- fallback (fp32 inputs, no ws) ----------------------------
constexpr int PSTR = 40;
__global__ __launch_bounds__(512, 4)
void attn_f16_slow(const float* __restrict__ Q, const float* __restrict__ K,
                   const float* __restrict__ V, const int* __restrict__ M,
                   float* __restrict__ O) {
    constexpr int S = 2048, D = 64;
    __shared__ __align__(16) _Float16 sP[8][16 * PSTR];
    __shared__ float sO[8][16 * 64];
    __shared__ float sL[8][16];
    const int tid = threadIdx.x, w = tid >> 6, lane = tid & 63;
    const int l15 = lane & 15, quad = lane >> 4;
    for (int phase = 0; phase < 2; ++phase) {
        const int batch = (int)blockIdx.y ^ phase;
        const int tile  = phase ? 127 - (int)blockIdx.x : (int)blockIdx.x;
        const int n_kt  = tile / 2 + 1;
        const int qg0   = tile * 16;
        const size_t bq = (size_t)batch * S;
        f16x8 qf[2];
        {
            const float* qp = Q + (bq + qg0 + l15) * D + quad * 8;
#pragma unroll
            for (int dc = 0; dc < 2; ++dc) {
                float4 x0 = *(const float4*)(qp + dc * 32);
                float4 x1 = *(const float4*)(qp + dc * 32 + 4);
                union { unsigned u[4]; f16x8 v; } t;
                t.u[0] = pack2h(x0.x, x0.y); t.u[1] = pack2h(x0.z, x0.w);
                t.u[2] = pack2h(x1.x, x1.y); t.u[3] = pack2h(x1.z, x1.w);
                qf[dc] = t.v;
            }
        }
        f32x4 acc[4]; float lacc[4];
#pragma unroll
        for (int c = 0; c < 4; ++c) { acc[c][0] = acc[c][1] = acc[c][2] = acc[c][3] = 0.f; }
#pragma unroll
        for (int r = 0; r < 4; ++r) lacc[r] = 0.f;
        for (int t = w; t < n_kt; t += 8) {
            const int kb = t * 32;
            f16x8 kf[2][2];
            {
                const float* kp = K + (bq + kb + l15) * D + quad * 8;
#pragma unroll
                for (int kg = 0; kg < 2; ++kg)
#pragma unroll
                    for (int dc = 0; dc < 2; ++dc) {
                        float4 x0 = *(const float4*)(kp + kg * 16 * D + dc * 32);
                        float4 x1 = *(const float4*)(kp + kg * 16 * D + dc * 32 + 4);
                        union { unsigned u[4]; f16x8 v; } tt;
                        tt.u[0] = pack2h(x0.x * CSCALE, x0.y * CSCALE);
                        tt.u[1] = pack2h(x0.z * CSCALE, x0.w * CSCALE);
                        tt.u[2] = pack2h(x1.x * CSCALE, x1.y * CSCALE);
                        tt.u[3] = pack2h(x1.z * CSCALE, x1.w * CSCALE);
                        kf[kg][dc] = tt.v;
                    }
            }
            float vr[4][8];
            {
                const float* vp = V + (bq + kb + quad * 8) * D + l15;
#pragma unroll
                for (int c = 0; c < 4; ++c)
#pragma unroll
                    for (int j = 0; j < 8; ++j)
                        vr[c][j] = vp[j * D + c * 16];
            }
            const int m0 = M[bq + kb + l15];
            const int m1 = M[bq + kb + 16 + l15];
            f32x4 sc[2];
#pragma unroll
            for (int kg = 0; kg < 2; ++kg) {
                f32x4 z; z[0] = z[1] = z[2] = z[3] = 0.f;
                z = MFMA_K32(qf[0], kf[kg][0], z);
                sc[kg] = MFMA_K32(qf[1], kf[kg][1], z);
            }
            float p[2][4];
#pragma unroll
            for (int kg = 0; kg < 2; ++kg) {
                const int key = kb + kg * 16 + l15;
                const int mv  = kg ? m1 : m0;
#pragma unroll
                for (int r = 0; r < 4; ++r) {
                    const int qrow = qg0 + quad * 4 + r;
                    float e  = __builtin_amdgcn_exp2f(sc[kg][r]);
                    bool  ok = (key <= qrow) && (mv != 0);
                    float pv = ok ? e : 0.f;
                    p[kg][r] = pv;
                    lacc[r] += pv;
                }
            }
            _Float16* sPw = sP[w];
#pragma unroll
            for (int kg = 0; kg < 2; ++kg)
#pragma unroll
                for (int r = 0; r < 4; ++r)
                    sPw[(quad * 4 + r) * PSTR + kg * 16 + l15] = (_Float16)p[kg][r];
            f16x8 pf = *(const f16x8*)(&sPw[l15 * PSTR + quad * 8]);
#pragma unroll
            for (int c = 0; c < 4; ++c) {
                union { unsigned u[4]; f16x8 v; } tt;
                tt.u[0] = pack2h(vr[c][0], vr[c][1]);
                tt.u[1] = pack2h(vr[c][2], vr[c][3]);
                tt.u[2] = pack2h(vr[c][4], vr[c][5]);
                tt.u[3] = pack2h(vr[c][6], vr[c][7]);
                acc[c] = MFMA_K32(pf, tt.v, acc[c]);
            }
        }
#pragma unroll
        for (int r = 0; r < 4; ++r) {
            float s = lacc[r];
            s += __shfl_xor(s, 1, 64);
            s += __shfl_xor(s, 2, 64);
            s += __shfl_xor(s, 4, 64);
            s += __shfl_xor(s, 8, 64);
            lacc[r] = s;
        }
#pragma unroll
        for (int c = 0; c < 4; ++c)
#pragma unroll
            for (int r = 0; r < 4; ++r)
                sO[w][(quad * 4 + r) * 64 + c * 16 + l15] = acc[c][r];
        if (l15 == 0) {
#pragma unroll
            for (int r = 0; r < 4; ++r) sL[w][quad * 4 + r] = lacc[r];
        }
        __syncthreads();
        {
            const int row = tid >> 5;
            const int col = (tid & 31) * 2;
            float a = 0.f, b = 0.f, l = 0.f;
#pragma unroll
            for (int w2 = 0; w2 < 8; ++w2) {
                a += sO[w2][row * 64 + col];
                b += sO[w2][row * 64 + col + 1];
                l += sL[w2][row];
            }
            const float inv = 1.f / fmaxf(l, 1e-37f);
            float2 o; o.x = a * inv; o.y = b * inv;
            *(float2*)(&O[(bq + qg0 + row) * D + col]) = o;
        }
        __syncthreads();
    }
}

extern "C" void kernel_launch(void* const* d_in, const int* in_sizes, int n_in,
                              void* d_out, int out_size, void* d_ws, size_t ws_size,
                              hipStream_t stream) {
    const float* Q = (const float*)d_in[0];
    const float* K = (const float*)d_in[1];
    const float* V = (const float*)d_in[2];
    const int*   M = (const int*)d_in[3];
    float*       O = (float*)d_out;
    const size_t n_kv = (size_t)8 * 2048 * 64;
    const size_t need = n_kv * 2 * sizeof(_Float16);   // Kh + Vq = 4 MB
    if (ws_size >= need) {
        _Float16* Kh = (_Float16*)d_ws;
        _Float16* Vq = Kh + n_kv;
        hipLaunchKernelGGL(prep_f16, dim3(256), dim3(256), 0, stream, K, V, Kh, Vq);
        hipLaunchKernelGGL(attn_f16_v5, dim3(64, 8), dim3(512), 0, stream, Q, Kh, Vq, M, O);
    } else {
        hipLaunchKernelGGL(attn_f16_slow, dim3(64, 8), dim3(512), 0, stream, Q, K, V, M, O);
    }
}

// Round 8
// 85.764 us; speedup vs baseline: 1.6427x; 1.6427x over previous
//
#include <hip/hip_runtime.h>

// ---------------------------------------------------------------------------
// Causal SDPA, B=8, S=2048, D=64, fp32 in/out.
//   prep_f16: K -> Kh (f16 row-major, pre-scaled by log2e/sqrt(D));
//             V -> Vq (f16 packed [B][S/16][64][16], coalesced PV frags);
//             M -> Mb (mask packed to bytes: 1 dword = 4 keys).
//   attn_f16_v6 = v5's 32-row supertile (2x reuse of K/V per loaded byte)
//     with the two R7 regressions fixed:
//       - __launch_bounds__(512,2): 256-VGPR cap -> NO scratch spills
//         (R7's 74 MB WRITE_SIZE was spill traffic from the (512,4) cap).
//       - two-phase balanced pairing restored: block (bx,by) does supertile
//         bx of batch by then 63-bx of batch by^1 -> exactly 65 iters/block,
//         grid 32x8 = 256 equal blocks (1/CU).
//     K register-prefetched 1 iter ahead; V + mask issued at top of iter
//     (consumed ~300cyc later, L2-covered); operand-swapped S^T = K·Q^T keeps
//     P in registers (no LDS in K-loop); no-max softmax, plain-sum split-K.
// Fallback (ws too small): R2-style kernel on fp32 inputs.
// ---------------------------------------------------------------------------

typedef _Float16 f16x8 __attribute__((ext_vector_type(8)));
typedef _Float16 f16x4 __attribute__((ext_vector_type(4)));
typedef float    f32x4 __attribute__((ext_vector_type(4)));

#define MFMA_K32(A, B, C) __builtin_amdgcn_mfma_f32_16x16x32_f16(A, B, C, 0, 0, 0)
#define MFMA_K16(A, B, C) __builtin_amdgcn_mfma_f32_16x16x16f16(A, B, C, 0, 0, 0)

__device__ inline unsigned pack2h(float a, float b) {
    union { _Float16 h[2]; unsigned u; } t;
    t.h[0] = (_Float16)a; t.h[1] = (_Float16)b;
    return t.u;
}

constexpr float CSCALE = 0.18033688011112042f;   // log2(e)/sqrt(64)

// -- prep: Kh = f16(K*CSCALE); Vq packed [B,S/16,64,16]; Mb byte mask -------
__global__ __launch_bounds__(256, 4)
void prep_f16(const float* __restrict__ K, const float* __restrict__ V,
              const int* __restrict__ M, _Float16* __restrict__ Kh,
              _Float16* __restrict__ Vq, unsigned char* __restrict__ Mb) {
    __shared__ _Float16 sT[64 * 80];          // [d][local_s]
    const int b   = blockIdx.x >> 5;
    const int s0  = (blockIdx.x & 31) * 64;
    const int t   = threadIdx.x;
    const int row = t >> 2;                   // local s 0..63
    const int grp = (t & 3) * 16;             // d group
    const size_t base = ((size_t)b * 2048 + s0 + row) * 64 + grp;
    {   // K: scale + convert, row-major
        union { _Float16 h[16]; f16x8 v[2]; } o;
        const float* p = K + base;
#pragma unroll
        for (int i = 0; i < 16; i += 4) {
            float4 x = *(const float4*)(p + i);
            o.h[i]   = (_Float16)(x.x * CSCALE); o.h[i+1] = (_Float16)(x.y * CSCALE);
            o.h[i+2] = (_Float16)(x.z * CSCALE); o.h[i+3] = (_Float16)(x.w * CSCALE);
        }
        *(f16x8*)(Kh + base) = o.v[0];
        *(f16x8*)(Kh + base + 8) = o.v[1];
    }
    {   // V: convert into LDS transposed sT[d][local_s]
        const float* p = V + base;
#pragma unroll
        for (int i = 0; i < 16; i += 4) {
            float4 x = *(const float4*)(p + i);
            sT[(grp + i    ) * 80 + row] = (_Float16)x.x;
            sT[(grp + i + 1) * 80 + row] = (_Float16)x.y;
            sT[(grp + i + 2) * 80 + row] = (_Float16)x.z;
            sT[(grp + i + 3) * 80 + row] = (_Float16)x.w;
        }
    }
    if (t < 64) {   // mask -> bytes
        const size_t s = (size_t)b * 2048 + s0 + t;
        Mb[s] = (unsigned char)(M[s] != 0);
    }
    __syncthreads();
    {   // Vq[b][s>>4][d][s&15]
        const int d = t & 63, g = t >> 6;
        const size_t o = (((size_t)b * 128 + (s0 >> 4) + g) * 64 + d) * 16;
        *(f16x8*)(Vq + o)     = *(const f16x8*)&sT[d * 80 + g * 16];
        *(f16x8*)(Vq + o + 8) = *(const f16x8*)&sT[d * 80 + g * 16 + 8];
    }
}

// -------- v6: 32-row supertile, balanced 2-phase, no spills ----------------
constexpr int SOSTR = 68;   // padded fp32 row stride for sO

__global__ __launch_bounds__(512, 2)
void attn_f16_v6(const float* __restrict__ Q, const _Float16* __restrict__ Kh,
                 const _Float16* __restrict__ Vq, const unsigned char* __restrict__ Mb,
                 float* __restrict__ O) {
    constexpr int S = 2048, D = 64;

    __shared__ float sO[8][32 * SOSTR];   // 69.6 KB partial O
    __shared__ float sL[8][32];           // partial denominators

    const int tid  = threadIdx.x;
    const int w    = tid >> 6;
    const int lane = tid & 63;
    const int l15  = lane & 15;
    const int quad = lane >> 4;

    for (int phase = 0; phase < 2; ++phase) {
        const int batch = (int)blockIdx.y ^ phase;
        const int st    = phase ? 63 - (int)blockIdx.x : (int)blockIdx.x;
        const int n_kt  = st + 1;                  // 32-key tiles (causal)
        const int qg0   = st * 32;
        const size_t bq = (size_t)batch * S;
        const _Float16* Kb = Kh + bq * D;
        const _Float16* Vb = Vq + bq * D;

        // Q fragments for the two 16-row frags: rows qg0 + f*16 + l15
        f16x8 qf[2][2];
#pragma unroll
        for (int f = 0; f < 2; ++f) {
            const float* qp = Q + (bq + qg0 + f * 16 + l15) * D + quad * 8;
#pragma unroll
            for (int dc = 0; dc < 2; ++dc) {
                float4 x0 = *(const float4*)(qp + dc * 32);
                float4 x1 = *(const float4*)(qp + dc * 32 + 4);
                union { unsigned u[4]; f16x8 v; } t;
                t.u[0] = pack2h(x0.x, x0.y); t.u[1] = pack2h(x0.z, x0.w);
                t.u[2] = pack2h(x1.x, x1.y); t.u[3] = pack2h(x1.z, x1.w);
                qf[f][dc] = t.v;
            }
        }

        f32x4 acc[2][4];
        float lacc[2] = {0.f, 0.f};
#pragma unroll
        for (int f = 0; f < 2; ++f)
#pragma unroll
            for (int c = 0; c < 4; ++c) { acc[f][c][0] = acc[f][c][1] = acc[f][c][2] = acc[f][c][3] = 0.f; }

        // ---- prime K prefetch for tile t = w -----------------------------
        f16x8 kn[2][2];
        if (w < n_kt) {
            const int kb = w * 32;
#pragma unroll
            for (int kg = 0; kg < 2; ++kg)
#pragma unroll
                for (int dc = 0; dc < 2; ++dc)
                    kn[kg][dc] = *(const f16x8*)(Kb + (size_t)(kb + kg * 16 + l15) * D + dc * 32 + quad * 8);
        }

        for (int t = w; t < n_kt; t += 8) {
            const int kb = t * 32;

            // ---- issue V + mask for THIS tile (used ~300cyc later) -------
            f16x4 vf[2][4];
#pragma unroll
            for (int kg = 0; kg < 2; ++kg)
#pragma unroll
                for (int c = 0; c < 4; ++c)
                    vf[kg][c] = *(const f16x4*)(Vb + ((size_t)((kb >> 4) + kg) * 64 + c * 16 + l15) * 16 + quad * 4);
            const unsigned um0 = *(const unsigned*)(Mb + bq + kb + quad * 4);
            const unsigned um1 = *(const unsigned*)(Mb + bq + kb + 16 + quad * 4);

            // ---- S^T = K Q^T on the prefetched K fragments ---------------
            f32x4 scT[2][2];   // [f][kg]
#pragma unroll
            for (int f = 0; f < 2; ++f) {
                f32x4 z; z[0] = z[1] = z[2] = z[3] = 0.f;
                f32x4 y0 = MFMA_K32(kn[0][0], qf[f][0], z);
                scT[f][0] = MFMA_K32(kn[0][1], qf[f][1], y0);
                f32x4 y1 = MFMA_K32(kn[1][0], qf[f][0], z);
                scT[f][1] = MFMA_K32(kn[1][1], qf[f][1], y1);
            }

            // ---- issue next tile's K loads -------------------------------
            if (t + 8 < n_kt) {
                const int kb2 = kb + 256;
#pragma unroll
                for (int kg = 0; kg < 2; ++kg)
#pragma unroll
                    for (int dc = 0; dc < 2; ++dc)
                        kn[kg][dc] = *(const f16x8*)(Kb + (size_t)(kb2 + kg * 16 + l15) * D + dc * 32 + quad * 8);
            }

            // ---- masked exp + PV for both q-frags ------------------------
#pragma unroll
            for (int f = 0; f < 2; ++f) {
                const int qrow = qg0 + f * 16 + l15;
                f16x4 pf0, pf1;
                {
                    union { _Float16 h[4]; f16x4 v; } pp;
#pragma unroll
                    for (int r = 0; r < 4; ++r) {
                        const int key = kb + quad * 4 + r;
                        float e  = __builtin_amdgcn_exp2f(scT[f][0][r]);
                        bool  ok = (key <= qrow) && (((um0 >> (8 * r)) & 0xFF) != 0);
                        float pv = ok ? e : 0.f;
                        lacc[f] += pv;
                        pp.h[r] = (_Float16)pv;
                    }
                    pf0 = pp.v;
#pragma unroll
                    for (int r = 0; r < 4; ++r) {
                        const int key = kb + 16 + quad * 4 + r;
                        float e  = __builtin_amdgcn_exp2f(scT[f][1][r]);
                        bool  ok = (key <= qrow) && (((um1 >> (8 * r)) & 0xFF) != 0);
                        float pv = ok ? e : 0.f;
                        lacc[f] += pv;
                        pp.h[r] = (_Float16)pv;
                    }
                    pf1 = pp.v;
                }
                acc[f][0] = MFMA_K16(pf0, vf[0][0], acc[f][0]);
                acc[f][1] = MFMA_K16(pf0, vf[0][1], acc[f][1]);
                acc[f][2] = MFMA_K16(pf0, vf[0][2], acc[f][2]);
                acc[f][3] = MFMA_K16(pf0, vf[0][3], acc[f][3]);
                acc[f][0] = MFMA_K16(pf1, vf[1][0], acc[f][0]);
                acc[f][1] = MFMA_K16(pf1, vf[1][1], acc[f][1]);
                acc[f][2] = MFMA_K16(pf1, vf[1][2], acc[f][2]);
                acc[f][3] = MFMA_K16(pf1, vf[1][3], acc[f][3]);
            }
        }

        // denom partials: sum over quads (lanes sharing l15)
#pragma unroll
        for (int f = 0; f < 2; ++f) {
            lacc[f] += __shfl_xor(lacc[f], 16, 64);
            lacc[f] += __shfl_xor(lacc[f], 32, 64);
        }

        // write partials, block-reduce, store
#pragma unroll
        for (int f = 0; f < 2; ++f)
#pragma unroll
            for (int c = 0; c < 4; ++c)
#pragma unroll
                for (int r = 0; r < 4; ++r)
                    sO[w][(f * 16 + quad * 4 + r) * SOSTR + c * 16 + l15] = acc[f][c][r];
        if (lane < 16) { sL[w][l15] = lacc[0]; sL[w][16 + l15] = lacc[1]; }
        __syncthreads();
        {
            const int row = tid >> 4;          // 0..31
            const int col = (tid & 15) * 4;    // 0,4,..,60
            float a0 = 0.f, a1 = 0.f, a2 = 0.f, a3 = 0.f, l = 0.f;
#pragma unroll
            for (int w2 = 0; w2 < 8; ++w2) {
                const float* p = &sO[w2][row * SOSTR + col];
                a0 += p[0]; a1 += p[1]; a2 += p[2]; a3 += p[3];
                l  += sL[w2][row];
            }
            const float inv = 1.f / fmaxf(l, 1e-37f);
            float4 o; o.x = a0 * inv; o.y = a1 * inv; o.z = a2 * inv; o.w = a3 * inv;
            *(float4*)(&O[(bq + qg0 + row) * D + col]) = o;
        }
        __syncthreads();   // sO/sL reused next phase
    }
}

// ---------------- fallback (fp32 inputs, no ws) ----------------------------
constexpr int PSTR = 40;
__global__ __launch_bounds__(512, 4)
void attn_f16_slow(const float* __restrict__ Q, const float* __restrict__ K,
                   const float* __restrict__ V, const int* __restrict__ M,
                   float* __restrict__ O) {
    constexpr int S = 2048, D = 64;
    __shared__ __align__(16) _Float16 sP[8][16 * PSTR];
    __shared__ float sO[8][16 * 64];
    __shared__ float sL[8][16];
    const int tid = threadIdx.x, w = tid >> 6, lane = tid & 63;
    const int l15 = lane & 15, quad = lane >> 4;
    for (int phase = 0; phase < 2; ++phase) {
        const int batch = (int)blockIdx.y ^ phase;
        const int tile  = phase ? 127 - (int)blockIdx.x : (int)blockIdx.x;
        const int n_kt  = tile / 2 + 1;
        const int qg0   = tile * 16;
        const size_t bq = (size_t)batch * S;
        f16x8 qf[2];
        {
            const float* qp = Q + (bq + qg0 + l15) * D + quad * 8;
#pragma unroll
            for (int dc = 0; dc < 2; ++dc) {
                float4 x0 = *(const float4*)(qp + dc * 32);
                float4 x1 = *(const float4*)(qp + dc * 32 + 4);
                union { unsigned u[4]; f16x8 v; } t;
                t.u[0] = pack2h(x0.x, x0.y); t.u[1] = pack2h(x0.z, x0.w);
                t.u[2] = pack2h(x1.x, x1.y); t.u[3] = pack2h(x1.z, x1.w);
                qf[dc] = t.v;
            }
        }
        f32x4 acc[4]; float lacc[4];
#pragma unroll
        for (int c = 0; c < 4; ++c) { acc[c][0] = acc[c][1] = acc[c][2] = acc[c][3] = 0.f; }
#pragma unroll
        for (int r = 0; r < 4; ++r) lacc[r] = 0.f;
        for (int t = w; t < n_kt; t += 8) {
            const int kb = t * 32;
            f16x8 kf[2][2];
            {
                const float* kp = K + (bq + kb + l15) * D + quad * 8;
#pragma unroll
                for (int kg = 0; kg < 2; ++kg)
#pragma unroll
                    for (int dc = 0; dc < 2; ++dc) {
                        float4 x0 = *(const float4*)(kp + kg * 16 * D + dc * 32);
                        float4 x1 = *(const float4*)(kp + kg * 16 * D + dc * 32 + 4);
                        union { unsigned u[4]; f16x8 v; } tt;
                        tt.u[0] = pack2h(x0.x * CSCALE, x0.y * CSCALE);
                        tt.u[1] = pack2h(x0.z * CSCALE, x0.w * CSCALE);
                        tt.u[2] = pack2h(x1.x * CSCALE, x1.y * CSCALE);
                        tt.u[3] = pack2h(x1.z * CSCALE, x1.w * CSCALE);
                        kf[kg][dc] = tt.v;
                    }
            }
            float vr[4][8];
            {
                const float* vp = V + (bq + kb + quad * 8) * D + l15;
#pragma unroll
                for (int c = 0; c < 4; ++c)
#pragma unroll
                    for (int j = 0; j < 8; ++j)
                        vr[c][j] = vp[j * D + c * 16];
            }
            const int m0 = M[bq + kb + l15];
            const int m1 = M[bq + kb + 16 + l15];
            f32x4 sc[2];
#pragma unroll
            for (int kg = 0; kg < 2; ++kg) {
                f32x4 z; z[0] = z[1] = z[2] = z[3] = 0.f;
                z = MFMA_K32(qf[0], kf[kg][0], z);
                sc[kg] = MFMA_K32(qf[1], kf[kg][1], z);
            }
            float p[2][4];
#pragma unroll
            for (int kg = 0; kg < 2; ++kg) {
                const int key = kb + kg * 16 + l15;
                const int mv  = kg ? m1 : m0;
#pragma unroll
                for (int r = 0; r < 4; ++r) {
                    const int qrow = qg0 + quad * 4 + r;
                    float e  = __builtin_amdgcn_exp2f(sc[kg][r]);
                    bool  ok = (key <= qrow) && (mv != 0);
                    float pv = ok ? e : 0.f;
                    p[kg][r] = pv;
                    lacc[r] += pv;
                }
            }
            _Float16* sPw = sP[w];
#pragma unroll
            for (int kg = 0; kg < 2; ++kg)
#pragma unroll
                for (int r = 0; r < 4; ++r)
                    sPw[(quad * 4 + r) * PSTR + kg * 16 + l15] = (_Float16)p[kg][r];
            f16x8 pf = *(const f16x8*)(&sPw[l15 * PSTR + quad * 8]);
#pragma unroll
            for (int c = 0; c < 4; ++c) {
                union { unsigned u[4]; f16x8 v; } tt;
                tt.u[0] = pack2h(vr[c][0], vr[c][1]);
                tt.u[1] = pack2h(vr[c][2], vr[c][3]);
                tt.u[2] = pack2h(vr[c][4], vr[c][5]);
                tt.u[3] = pack2h(vr[c][6], vr[c][7]);
                acc[c] = MFMA_K32(pf, tt.v, acc[c]);
            }
        }
#pragma unroll
        for (int r = 0; r < 4; ++r) {
            float s = lacc[r];
            s += __shfl_xor(s, 1, 64);
            s += __shfl_xor(s, 2, 64);
            s += __shfl_xor(s, 4, 64);
            s += __shfl_xor(s, 8, 64);
            lacc[r] = s;
        }
#pragma unroll
        for (int c = 0; c < 4; ++c)
#pragma unroll
            for (int r = 0; r < 4; ++r)
                sO[w][(quad * 4 + r) * 64 + c * 16 + l15] = acc[c][r];
        if (l15 == 0) {
#pragma unroll
            for (int r = 0; r < 4; ++r) sL[w][quad * 4 + r] = lacc[r];
        }
        __syncthreads();
        {
            const int row = tid >> 5;
            const int col = (tid & 31) * 2;
            float a = 0.f, b = 0.f, l = 0.f;
#pragma unroll
            for (int w2 = 0; w2 < 8; ++w2) {
                a += sO[w2][row * 64 + col];
                b += sO[w2][row * 64 + col + 1];
                l += sL[w2][row];
            }
            const float inv = 1.f / fmaxf(l, 1e-37f);
            float2 o; o.x = a * inv; o.y = b * inv;
            *(float2*)(&O[(bq + qg0 + row) * D + col]) = o;
        }
        __syncthreads();
    }
}

extern "C" void kernel_launch(void* const* d_in, const int* in_sizes, int n_in,
                              void* d_out, int out_size, void* d_ws, size_t ws_size,
                              hipStream_t stream) {
    const float* Q = (const float*)d_in[0];
    const float* K = (const float*)d_in[1];
    const float* V = (const float*)d_in[2];
    const int*   M = (const int*)d_in[3];
    float*       O = (float*)d_out;
    const size_t n_kv = (size_t)8 * 2048 * 64;
    const size_t need = n_kv * 2 * sizeof(_Float16) + 8 * 2048;  // Kh+Vq+Mb
    if (ws_size >= need) {
        _Float16* Kh = (_Float16*)d_ws;
        _Float16* Vq = Kh + n_kv;
        unsigned char* Mb = (unsigned char*)(Vq + n_kv);
        hipLaunchKernelGGL(prep_f16, dim3(256), dim3(256), 0, stream, K, V, M, Kh, Vq, Mb);
        hipLaunchKernelGGL(attn_f16_v6, dim3(32, 8), dim3(512), 0, stream, Q, Kh, Vq, Mb, O);
    } else {
        hipLaunchKernelGGL(attn_f16_slow, dim3(64, 8), dim3(512), 0, stream, Q, K, V, M, O);
    }
}